// Round 1
// baseline (272.681 us; speedup 1.0000x reference)
//
#include <hip/hip_runtime.h>
#include <stdint.h>

#define D_  1024
#define S_  2048
#define B_  2
#define H_  16
#define HD_ 64
#define M_  (B_*S_)   // 4096

typedef unsigned short u16;
typedef __attribute__((ext_vector_type(8))) __bf16 bf16x8;
typedef __attribute__((ext_vector_type(4))) float  f32x4;

__device__ __forceinline__ u16 f2bf(float f) {
    union { float f; uint32_t u; } x; x.f = f;
    uint32_t r = x.u + 0x7fffu + ((x.u >> 16) & 1u);   // RNE
    return (u16)(r >> 16);
}

__device__ __forceinline__ void gload_lds16(const void* g, void* l) {
    __builtin_amdgcn_global_load_lds(
        (const __attribute__((address_space(1))) uint32_t*)g,
        (__attribute__((address_space(3))) uint32_t*)l, 16, 0, 0);
}

// ---------------- fp32 -> bf16 convert (vectorized) ----------------
__global__ __launch_bounds__(256) void cvt_kernel(const float* __restrict__ in,
                                                  u16* __restrict__ out) {
    int i = (blockIdx.x * 256 + threadIdx.x) * 4;
    float4 v = *(const float4*)(in + i);
    ushort4 o;
    o.x = f2bf(v.x); o.y = f2bf(v.y); o.z = f2bf(v.z); o.w = f2bf(v.w);
    *(ushort4*)(out + i) = o;
}

// ---------------- W (K,N) fp32 -> Wt (N,K) bf16 ----------------
__global__ __launch_bounds__(256) void transpose_w(const float* __restrict__ W,
                                                   u16* __restrict__ Wt) {
    __shared__ u16 t[64][65];
    int k0 = blockIdx.x * 64, n0 = blockIdx.y * 64;
    int tid = threadIdx.x;
    int c4 = (tid & 15) * 4, r = tid >> 4;          // r: 0..15
#pragma unroll
    for (int i = 0; i < 4; i++) {
        int row = r + i * 16;                        // k-local
        float4 v = *(const float4*)(W + (uint64_t)(k0 + row) * D_ + n0 + c4);
        t[row][c4 + 0] = f2bf(v.x);
        t[row][c4 + 1] = f2bf(v.y);
        t[row][c4 + 2] = f2bf(v.z);
        t[row][c4 + 3] = f2bf(v.w);
    }
    __syncthreads();
#pragma unroll
    for (int i = 0; i < 4; i++) {
        int nrow = r + i * 16;                       // n-local
        ushort4 o;
        o.x = t[c4 + 0][nrow]; o.y = t[c4 + 1][nrow];
        o.z = t[c4 + 2][nrow]; o.w = t[c4 + 3][nrow];
        *(ushort4*)(Wt + (uint64_t)(n0 + nrow) * D_ + k0 + c4) = o;
    }
}

// ---------------- QKV projection GEMM (m97 structure, 128x128, BK=32) -------
// C[m][n] = sum_k X[m][k] * Wt[n][k] + bias[n];  scatter per projection.
__global__ __launch_bounds__(256) void gemm_qkv(
    const u16* __restrict__ Xq, const u16* __restrict__ Xk, const u16* __restrict__ Xv,
    const u16* __restrict__ Wtq, const u16* __restrict__ Wtk, const u16* __restrict__ Wtv,
    const float* __restrict__ bq, const float* __restrict__ bk, const float* __restrict__ bv,
    u16* __restrict__ Qo, u16* __restrict__ Ko, u16* __restrict__ Vo)
{
    int p = blockIdx.z;
    const u16* X    = p == 0 ? Xq  : (p == 1 ? Xk  : Xv);
    const u16* Wt   = p == 0 ? Wtq : (p == 1 ? Wtk : Wtv);
    const float* bias = p == 0 ? bq : (p == 1 ? bk : bv);
    u16* out = p == 0 ? Qo : (p == 1 ? Ko : Vo);
    float scale = p == 0 ? 0.125f : 1.0f;   // fold 1/sqrt(HD) into Q

    __shared__ __align__(16) u16 As[128 * 32];
    __shared__ __align__(16) u16 Bs[128 * 32];

    int tid = threadIdx.x;
    int lane = tid & 63, wid = tid >> 6;
    int lrow = lane & 15, lk = lane >> 4;   // lk: 0..3
    int wr = wid >> 1, wc = wid & 1;
    int bm = blockIdx.x, bn = blockIdx.y;

    f32x4 acc[4][4] = {};

    const uint64_t Xrow0 = (uint64_t)bm * 128 * D_;
    const uint64_t Wrow0 = (uint64_t)bn * 128 * D_;

    for (int kt = 0; kt < D_ / 32; ++kt) {
        int k0 = kt * 32;
#pragma unroll
        for (int it = 0; it < 2; ++it) {
            int i = it * 256 + tid;
            int row = i >> 2, cc = i & 3;   // 4 x 16B chunks per 32-elem row
            gload_lds16(X  + Xrow0 + (uint64_t)row * D_ + k0 + cc * 8,
                        (char*)As + it * 4096 + wid * 1024);
            gload_lds16(Wt + Wrow0 + (uint64_t)row * D_ + k0 + cc * 8,
                        (char*)Bs + it * 4096 + wid * 1024);
        }
        __syncthreads();
        bf16x8 a[4], b[4];
#pragma unroll
        for (int m = 0; m < 4; m++)
            a[m] = *(const bf16x8*)((const char*)As + (wr * 64 + m * 16 + lrow) * 64 + lk * 16);
#pragma unroll
        for (int n = 0; n < 4; n++)
            b[n] = *(const bf16x8*)((const char*)Bs + (wc * 64 + n * 16 + lrow) * 64 + lk * 16);
#pragma unroll
        for (int m = 0; m < 4; m++)
#pragma unroll
            for (int n = 0; n < 4; n++)
                acc[m][n] = __builtin_amdgcn_mfma_f32_16x16x32_bf16(a[m], b[n], acc[m][n], 0, 0, 0);
        __syncthreads();
    }

    // epilogue: + bias, * scale, scatter to attention layouts (bf16)
#pragma unroll
    for (int m = 0; m < 4; m++) {
        int grow_base = bm * 128 + wr * 64 + m * 16 + lk * 4;
#pragma unroll
        for (int n = 0; n < 4; n++) {
            int gcol = bn * 128 + wc * 64 + n * 16 + lrow;
            float bb = bias[gcol];
            int h = gcol >> 6, hd = gcol & 63;
#pragma unroll
            for (int j = 0; j < 4; j++) {
                int grow = grow_base + j;
                int b_ = grow >> 11, s = grow & 2047;
                u16 o16 = f2bf((acc[m][n][j] + bb) * scale);
                if (p < 2)  // Q, K: [BH][S][HD]
                    out[(((uint64_t)(b_ * H_ + h)) * S_ + s) * HD_ + hd] = o16;
                else        // V transposed: [BH][HD][S]
                    out[(((uint64_t)(b_ * H_ + h)) * HD_ + hd) * S_ + s] = o16;
            }
        }
    }
}

// ---------------- flash attention: QBLK=128 (4 waves x 32 rows), KVBLK=64 ---
__global__ __launch_bounds__(256) void attn_kernel(
    const u16* __restrict__ Q, const u16* __restrict__ K,
    const u16* __restrict__ VT, float* __restrict__ out)
{
    __shared__ __align__(16) u16 Ks[64 * 64];       // 8 KB, swizzled
    __shared__ __align__(16) u16 Vs[64 * 64];       // 8 KB, swizzled (VT tile)
    __shared__ __align__(16) u16 Ps[4 * 32 * 64];   // 16 KB, per-wave swizzled

    int tid = threadIdx.x;
    int lane = tid & 63, wid = tid >> 6;
    int lrow = lane & 15, lk = lane >> 4;
    int qt = blockIdx.x, bh = blockIdx.y;

    // Q fragments in registers (Q already scaled by 1/8)
    bf16x8 qf[2][2];
    const uint64_t qrow0 = (uint64_t)bh * S_ + qt * 128 + wid * 32;
#pragma unroll
    for (int mt = 0; mt < 2; mt++)
#pragma unroll
        for (int kk = 0; kk < 2; kk++)
            qf[mt][kk] = *(const bf16x8*)(Q + (qrow0 + mt * 16 + lrow) * HD_ + kk * 32 + lk * 8);

    f32x4 o_acc[2][4] = {};
    f32x4 m_run[2], l_run[2];
#pragma unroll
    for (int mt = 0; mt < 2; mt++)
#pragma unroll
        for (int j = 0; j < 4; j++) { m_run[mt][j] = -1e30f; l_run[mt][j] = 0.f; }

    const char* Kbase = (const char*)(K  + (uint64_t)bh * S_ * HD_);
    const char* Vbase = (const char*)(VT + (uint64_t)bh * HD_ * S_);

    for (int t = 0; t < S_ / 64; ++t) {
        int kv0 = t * 64;
        // stage K and VT tiles: linear LDS dest, pre-swizzled global source
#pragma unroll
        for (int it = 0; it < 2; ++it) {
            int i = it * 256 + tid;
            int o = i * 16;
            int os = o ^ (((o >> 7) & 7) << 4);      // involution swizzle
            gload_lds16(Kbase + (uint64_t)kv0 * 128 + os,
                        (char*)Ks + it * 4096 + wid * 1024);
            int hd = os >> 7, sb = os & 127;
            gload_lds16(Vbase + (uint64_t)hd * (S_ * 2) + kv0 * 2 + sb,
                        (char*)Vs + it * 4096 + wid * 1024);
        }
        __syncthreads();

        // S = Q K^T  (swizzled reads)
        f32x4 sacc[2][4] = {};
        bf16x8 kf[4][2];
#pragma unroll
        for (int c = 0; c < 4; c++) {
            int kvr = c * 16 + lrow;
#pragma unroll
            for (int kk = 0; kk < 2; kk++) {
                int o = kvr * 128 + kk * 64 + lk * 16;
                kf[c][kk] = *(const bf16x8*)((const char*)Ks + (o ^ ((kvr & 7) << 4)));
            }
        }
#pragma unroll
        for (int mt = 0; mt < 2; mt++)
#pragma unroll
            for (int c = 0; c < 4; c++)
#pragma unroll
                for (int kk = 0; kk < 2; kk++)
                    sacc[mt][c] = __builtin_amdgcn_mfma_f32_16x16x32_bf16(
                        qf[mt][kk], kf[c][kk], sacc[mt][c], 0, 0, 0);

        // V fragments (independent of P)
        bf16x8 vf[4][2];
#pragma unroll
        for (int c2 = 0; c2 < 4; c2++) {
            int hd = c2 * 16 + lrow;
#pragma unroll
            for (int ks = 0; ks < 2; ks++) {
                int o = hd * 128 + ks * 64 + lk * 16;
                vf[c2][ks] = *(const bf16x8*)((const char*)Vs + (o ^ ((hd & 7) << 4)));
            }
        }

        // online softmax (rows live in 16-lane groups; butterfly over 1,2,4,8)
        char* Pw = (char*)Ps + wid * 4096;
#pragma unroll
        for (int mt = 0; mt < 2; mt++) {
            f32x4 tmax = sacc[mt][0];
#pragma unroll
            for (int c = 1; c < 4; c++)
#pragma unroll
                for (int j = 0; j < 4; j++) tmax[j] = fmaxf(tmax[j], sacc[mt][c][j]);
#pragma unroll
            for (int off = 1; off < 16; off <<= 1)
#pragma unroll
                for (int j = 0; j < 4; j++)
                    tmax[j] = fmaxf(tmax[j], __shfl_xor(tmax[j], off, 64));

            f32x4 mnew, sc;
#pragma unroll
            for (int j = 0; j < 4; j++) {
                mnew[j] = fmaxf(m_run[mt][j], tmax[j]);
                sc[j] = __expf(m_run[mt][j] - mnew[j]);
            }
            f32x4 pr[4];
            f32x4 tsum = {0.f, 0.f, 0.f, 0.f};
#pragma unroll
            for (int c = 0; c < 4; c++)
#pragma unroll
                for (int j = 0; j < 4; j++) {
                    pr[c][j] = __expf(sacc[mt][c][j] - mnew[j]);
                    tsum[j] += pr[c][j];
                }
#pragma unroll
            for (int off = 1; off < 16; off <<= 1)
#pragma unroll
                for (int j = 0; j < 4; j++) tsum[j] += __shfl_xor(tsum[j], off, 64);
#pragma unroll
            for (int j = 0; j < 4; j++)
                l_run[mt][j] = l_run[mt][j] * sc[j] + tsum[j];
#pragma unroll
            for (int c2 = 0; c2 < 4; c2++)
#pragma unroll
                for (int j = 0; j < 4; j++) o_acc[mt][c2][j] *= sc[j];
            m_run[mt] = mnew;

            // write P tile (bf16) to per-wave swizzled LDS
#pragma unroll
            for (int c = 0; c < 4; c++)
#pragma unroll
                for (int j = 0; j < 4; j++) {
                    int ql = mt * 16 + lk * 4 + j;
                    int o = ql * 128 + (c * 16 + lrow) * 2;
                    *(u16*)(Pw + (o ^ ((ql & 7) << 4))) = f2bf(pr[c][j]);
                }
        }

        // O += P V  (P re-fragmented through LDS; same-wave dep -> lgkmcnt only)
#pragma unroll
        for (int mt = 0; mt < 2; mt++) {
            bf16x8 pa[2];
#pragma unroll
            for (int ks = 0; ks < 2; ks++) {
                int ql = mt * 16 + lrow;
                int o = ql * 128 + ks * 64 + lk * 16;
                pa[ks] = *(const bf16x8*)((const char*)Ps + wid * 4096 + (o ^ ((ql & 7) << 4)));
            }
#pragma unroll
            for (int c2 = 0; c2 < 4; c2++)
#pragma unroll
                for (int ks = 0; ks < 2; ks++)
                    o_acc[mt][c2] = __builtin_amdgcn_mfma_f32_16x16x32_bf16(
                        pa[ks], vf[c2][ks], o_acc[mt][c2], 0, 0, 0);
        }
        __syncthreads();
    }

    // normalize + write fp32 output [B][S][D]
    int b_ = bh >> 4, h = bh & 15;
#pragma unroll
    for (int mt = 0; mt < 2; mt++)
#pragma unroll
        for (int c2 = 0; c2 < 4; c2++)
#pragma unroll
            for (int j = 0; j < 4; j++) {
                int s = qt * 128 + wid * 32 + mt * 16 + lk * 4 + j;
                int hd = c2 * 16 + lrow;
                out[((uint64_t)(b_ * S_ + s)) * D_ + h * HD_ + hd] =
                    o_acc[mt][c2][j] / l_run[mt][j];
            }
}

// ---------------- launcher ----------------
extern "C" void kernel_launch(void* const* d_in, const int* in_sizes, int n_in,
                              void* d_out, int out_size, void* d_ws, size_t ws_size,
                              hipStream_t stream) {
    const float* q  = (const float*)d_in[0];
    const float* k  = (const float*)d_in[1];
    const float* v  = (const float*)d_in[2];
    const float* Wq = (const float*)d_in[3];
    const float* bq = (const float*)d_in[4];
    const float* Wk = (const float*)d_in[5];
    const float* bk = (const float*)d_in[6];
    const float* Wv = (const float*)d_in[7];
    const float* bv = (const float*)d_in[8];
    float* out = (float*)d_out;

    u16* ws = (u16*)d_ws;
    const size_t XN = (size_t)M_ * D_;   // 4 Mi elems
    const size_t WN = (size_t)D_ * D_;   // 1 Mi elems
    u16* Xq  = ws;          u16* Xk  = Xq  + XN;  u16* Xv  = Xk  + XN;
    u16* Wtq = Xv + XN;     u16* Wtk = Wtq + WN;  u16* Wtv = Wtk + WN;
    u16* Qb  = Wtv + WN;    u16* Kb  = Qb  + XN;  u16* Vb  = Kb  + XN;

    cvt_kernel<<<XN / 1024, 256, 0, stream>>>(q, Xq);
    cvt_kernel<<<XN / 1024, 256, 0, stream>>>(k, Xk);
    cvt_kernel<<<XN / 1024, 256, 0, stream>>>(v, Xv);
    transpose_w<<<dim3(16, 16), 256, 0, stream>>>(Wq, Wtq);
    transpose_w<<<dim3(16, 16), 256, 0, stream>>>(Wk, Wtk);
    transpose_w<<<dim3(16, 16), 256, 0, stream>>>(Wv, Wtv);
    gemm_qkv<<<dim3(32, 8, 3), 256, 0, stream>>>(Xq, Xk, Xv, Wtq, Wtk, Wtv,
                                                 bq, bk, bv, Qb, Kb, Vb);
    attn_kernel<<<dim3(16, 32), 256, 0, stream>>>(Qb, Kb, Vb, out);
}